// Round 4
// baseline (678.414 us; speedup 1.0000x reference)
//
#include <hip/hip_runtime.h>
#include <math.h>

// Program interpreter: B=1M rows, 19 steps of MLP(2->64->64->3) + argmax walk.
// fp32 emulated on f16 MFMA, 2-limb splits (lo limb scaled 2^12, RTZ pack).
//
// R12: single-variable experiment on the accB MFMA chain. Cycle accounting
// (R8-R11) shows wall/step ~2676 cyc for a 2-wave batch vs only ~760 cyc of
// issue work -> dependency-latency-bound. Largest suspect chain segment: the
// 4-deep dependent MFMA accB chain (280-560 cyc at 70-140 cyc dependent
// latency). Change vs the 632us R8 baseline: accB = two independent 2-deep
// MFMA chains merged by pk_add (association proven numerically safe by R9's
// pass: absmax identical). Everything else byte-identical to R8 -- no
// setprio (R11: null), DS butterfly reduce (R9: permlane was not the win),
// separate h2p combine. Pre-committed read: -8..-18% => chain model holds;
// +-2% => MFMA chain not dominant, attack dots/reduce chain next.

#define NSTEPS 19

typedef _Float16 half8   __attribute__((ext_vector_type(8)));
typedef _Float16 half2v  __attribute__((ext_vector_type(2)));
typedef float    float2v __attribute__((ext_vector_type(2)));
typedef float    float4v __attribute__((ext_vector_type(4)));

__device__ __forceinline__ half2v pkrtz(float a, float b) {
    return __builtin_bit_cast(half2v, __builtin_amdgcn_cvt_pkrtz(a, b));
}
__device__ __forceinline__ float swz_xor16(float v) {
    // BitMode: and=0x1F, or=0, xor=16 -> lane' = lane ^ 16 (within 32-group)
    int r = __builtin_amdgcn_ds_swizzle(__builtin_bit_cast(int, v), 0x401F);
    return __builtin_bit_cast(float, r);
}
__device__ __forceinline__ float2v lo2(float4v v) {
    return __builtin_shufflevector(v, v, 0, 1);
}
__device__ __forceinline__ float2v hi2(float4v v) {
    return __builtin_shufflevector(v, v, 2, 3);
}

__global__ __launch_bounds__(256, 2)
void program_kernel(const float* __restrict__ x,
                    const float* __restrict__ W1,
                    const float* __restrict__ b1,
                    const float* __restrict__ W2,
                    const float* __restrict__ b2,
                    const float* __restrict__ W3,
                    const float* __restrict__ b3,
                    float* __restrict__ out,
                    int B) {
    const int tid    = threadIdx.x;
    const int lane   = tid & 63;
    const int wave   = tid >> 6;
    const int lanelo = lane & 15;   // m: my batch row within the tile
    const int q8     = lane >> 4;   // k-slice / replica group 0..3
    const int myRow  = blockIdx.x * 64 + wave * 16 + lanelo;
    const int rowLd  = myRow < B ? myRow : (B - 1);

    // ---- w1 tables as pairs (VGPR): pair i of kf-half: k = kf*32+q8*8+2i ----
    float2v w1a[8], w1b[8], b1v[8];
    #pragma unroll
    for (int kf = 0; kf < 2; ++kf) {
        const int k0 = kf * 32 + q8 * 8;
        const float2v* a = (const float2v*)(W1 + k0);
        const float2v* bb = (const float2v*)(W1 + 64 + k0);
        const float2v* bv = (const float2v*)(b1 + k0);
        #pragma unroll
        for (int i = 0; i < 4; ++i) {
            w1a[kf * 4 + i] = a[i];
            w1b[kf * 4 + i] = bb[i];
            b1v[kf * 4 + i] = bv[i];
        }
    }

    // ---- W2^T limb A-frags (MFMA-only; AGPR-eligible) ----
    half8 Wh[2][4], Wl[2][4];
    #pragma unroll
    for (int kf = 0; kf < 2; ++kf) {
        #pragma unroll
        for (int t = 0; t < 4; ++t) {
            half8 bh, bl;
            #pragma unroll
            for (int j = 0; j < 8; ++j) {
                const float w =
                    W2[(kf * 32 + q8 * 8 + j) * 64 + t * 16 + lanelo];
                const _Float16 wh = (_Float16)w;                       // RNE
                const _Float16 wl = (_Float16)((w - (float)wh) * 4096.0f);
                bh[j] = wh;
                bl[j] = wl;
            }
            Wh[kf][t] = bh;
            Wl[kf][t] = bl;
        }
    }

    // ---- b2 C-init frags (MFMA-C only) ----
    float4v b2f[4];
    #pragma unroll
    for (int t = 0; t < 4; ++t) {
        const int n = t * 16 + q8 * 4;
        b2f[t] = (float4v){b2[n], b2[n + 1], b2[n + 2], b2[n + 3]};
    }

    // ---- W3 difference tables (VGPR): my n-set n = 16t+4*q8+r, pairs ----
    float2v d10[8], d20[8];
    #pragma unroll
    for (int p = 0; p < 8; ++p) {
        const int n0 = (p >> 1) * 16 + q8 * 4 + (p & 1) * 2;
        const float w00 = W3[n0 * 3 + 0],       w01 = W3[n0 * 3 + 1];
        const float w02 = W3[n0 * 3 + 2];
        const float w10 = W3[(n0 + 1) * 3 + 0], w11 = W3[(n0 + 1) * 3 + 1];
        const float w12 = W3[(n0 + 1) * 3 + 2];
        d10[p] = (float2v){w01 - w00, w11 - w10};
        d20[p] = (float2v){w02 - w00, w12 - w10};
    }
    const float b3v0 = b3[0];
    const float db10 = b3[1] - b3[0];
    const float db20 = b3[2] - b3[0];

    // ---- initial row state (4x replicated across q8 groups) ----
    float pos, fwd, c5;
    {
        const float* xr = x + (size_t)rowLd * 6;
        pos = xr[0];
        fwd = xr[1];
        c5  = xr[5];
    }

    const float4v zf = {0.f, 0.f, 0.f, 0.f};
    const float2v z2 = {0.f, 0.f};
    const float2v kinv = {1.0f / 4096.0f, 1.0f / 4096.0f};
    float l0 = 0.f, l1 = 0.f, l2 = 0.f;

    #pragma unroll 1
    for (int step = 0; step < NSTEPS; ++step) {
        // ---- layer 1 (packed) + 2-limb split -> B-frag limbs ----
        const float2v posp = {pos, pos}, fwdp = {fwd, fwd};
        half8 Hh[2], Hl[2];
        #pragma unroll
        for (int kf = 0; kf < 2; ++kf) {
            union { half8 v; half2v h2[4]; } uh, ul;
            #pragma unroll
            for (int p = 0; p < 4; ++p) {
                const int e = kf * 4 + p;
                float2v z = __builtin_elementwise_fma(fwdp, w1b[e], b1v[e]);
                z = __builtin_elementwise_fma(posp, w1a[e], z);
                const float2v hp = __builtin_elementwise_max(z, z2);
                uh.h2[p] = pkrtz(hp[0], hp[1]);
                // residuals (hi-half f16 extract folds into v_fma_mix)
                const float r0 = fmaf((float)uh.h2[p][0], -1.0f, hp[0]);
                const float r1 = fmaf((float)uh.h2[p][1], -1.0f, hp[1]);
                const float2v rp = (float2v){r0, r1} * 4096.0f;  // pk_mul
                ul.h2[p] = pkrtz(rp[0], rp[1]);
            }
            Hh[kf] = uh.v;
            Hl[kf] = ul.v;
        }

        // ---- layer 2 via MFMA: accB as two independent 2-deep chains ----
        // (R12's one change vs R8: cuts 2 dependent-MFMA latencies off the
        //  per-step critical path; merge via pk_add, association R9-proven.)
        float4v accA[4], accB1[4], accB2[4];
        #pragma unroll
        for (int t = 0; t < 4; ++t) {
            accB1[t] = __builtin_amdgcn_mfma_f32_16x16x32_f16(
                Wl[0][t], Hh[0], zf, 0, 0, 0);
            accB1[t] = __builtin_amdgcn_mfma_f32_16x16x32_f16(
                Wh[0][t], Hl[0], accB1[t], 0, 0, 0);
            accB2[t] = __builtin_amdgcn_mfma_f32_16x16x32_f16(
                Wl[1][t], Hh[1], zf, 0, 0, 0);
            accB2[t] = __builtin_amdgcn_mfma_f32_16x16x32_f16(
                Wh[1][t], Hl[1], accB2[t], 0, 0, 0);
            accA[t] = __builtin_amdgcn_mfma_f32_16x16x32_f16(
                Wh[0][t], Hh[0], b2f[t], 0, 0, 0);
            accA[t] = __builtin_amdgcn_mfma_f32_16x16x32_f16(
                Wh[1][t], Hh[1], accA[t], 0, 0, 0);
        }

        // ---- h2 (packed combine+relu) ----
        float2v h2p[8];
        #pragma unroll
        for (int t = 0; t < 4; ++t) {
            const float4v aB = accB1[t] + accB2[t];            // 2x pk_add
            h2p[2 * t] = __builtin_elementwise_max(
                __builtin_elementwise_fma(lo2(aB), kinv, lo2(accA[t])),
                z2);
            h2p[2 * t + 1] = __builtin_elementwise_max(
                __builtin_elementwise_fma(hi2(aB), kinv, hi2(accA[t])),
                z2);
        }

        // ---- difference dots (packed) + cross-replica reduce ----
        float2v s1 = z2, s2 = z2;
        #pragma unroll
        for (int p = 0; p < 8; ++p) {
            s1 = __builtin_elementwise_fma(h2p[p], d10[p], s1);
            s2 = __builtin_elementwise_fma(h2p[p], d20[p], s2);
        }
        float g10 = s1[0] + s1[1];
        float g20 = s2[0] + s2[1];
        g10 += swz_xor16(g10);
        g20 += swz_xor16(g20);
        g10 += __shfl_xor(g10, 32, 64);
        g20 += __shfl_xor(g20, 32, 64);
        g10 += db10;   // = l1 - l0
        g20 += db20;   // = l2 - l0

        // ---- last step: reconstruct full logits for the output probs ----
        if (step == NSTEPS - 1) {
            float2v s0 = z2;
            #pragma unroll
            for (int p = 0; p < 8; ++p) {
                const int n0 = (p >> 1) * 16 + q8 * 4 + (p & 1) * 2;
                const float2v w30 = {W3[n0 * 3], W3[(n0 + 1) * 3]};
                s0 = __builtin_elementwise_fma(h2p[p], w30, s0);
            }
            float t0 = s0[0] + s0[1];
            t0 += swz_xor16(t0);
            t0 += __shfl_xor(t0, 32, 64);
            l0 = t0 + b3v0;
            l1 = l0 + g10;
            l2 = l0 + g20;
        }

        // ---- decision: l2 > max(l0,l1) <=> g20 > max(0,g10);
        //      l1 > l0 <=> g10 > 0 (first-max-wins preserved) ----
        const float delta =
            (g20 > fmaxf(0.f, g10)) ? 1.0f : ((g10 > 0.f) ? 0.0f : -1.0f);
        pos += delta;
        fwd += 1.0f;
    }

    // ---- epilogue: all lanes have their row's logits; q8==0 stores ----
    if (q8 == 0 && myRow < B) {
        const float p0 = 1.f / (1.f + __expf(-l0));
        const float p1 = 1.f / (1.f + __expf(-l1));
        const float p2 = 1.f / (1.f + __expf(-l2));
        float2* o = (float2*)(out + (size_t)myRow * 6);
        o[0] = make_float2(pos, fwd);
        o[1] = make_float2(p0, p1);
        o[2] = make_float2(p2, c5 + (float)NSTEPS);
    }
}

extern "C" void kernel_launch(void* const* d_in, const int* in_sizes, int n_in,
                              void* d_out, int out_size, void* d_ws, size_t ws_size,
                              hipStream_t stream) {
    const float* x  = (const float*)d_in[0];
    const float* W1 = (const float*)d_in[1];
    const float* b1 = (const float*)d_in[2];
    const float* W2 = (const float*)d_in[3];
    const float* b2 = (const float*)d_in[4];
    const float* W3 = (const float*)d_in[5];
    const float* b3 = (const float*)d_in[6];
    float* out = (float*)d_out;

    const int B = in_sizes[0] / 6;              // 1048576
    const int nBlocks = (B + 63) / 64;          // 64 rows/block (4 waves x 16)

    program_kernel<<<nBlocks, 256, 0, stream>>>(
        x, W1, b1, W2, b2, W3, b3, out, B);
}

// Round 5
// 636.078 us; speedup vs baseline: 1.0666x; 1.0666x over previous
//
#include <hip/hip_runtime.h>
#include <math.h>

// Program interpreter: B=1M rows, 19 steps of MLP(2->64->64->3) + argmax walk.
// fp32 emulated on f16 MFMA, 2-limb splits (lo limb scaled 2^12, RTZ pack).
//
// R13: wave de-phasing. Calibrated model (R8-R12): VALUBusy+MfmaUtil ~= 100%
// of wall; one 16x16x32 f16 MFMA = ~19.4 cyc of MFMA-pipe time (2075 TF
// ubench / 1024 SIMD / 2.4GHz), so per 2-wave step VALU(~1742)+MFMA(~890)
// ~= wall(2700): pipes are never concurrent. The two co-resident waves run
// identical data-independent-duration code -> phase-locked: both in MFMA-wait
// together (VALU idle), both in VALU together (MFMA idle). setprio (R11) was
// null because the lock is symmetric. Fix: one-time half-step stagger -- odd
// hardware wave-slot sleeps ~640 cyc before the step loop; with no barriers
// and uniform step durations the anti-phase persists for all 19 steps, so
// wave A's MFMA drain runs under wave B's VALU phase. Math bitwise identical
// to the 632us R8 kernel (R12 chain-split reverted): absmax must stay
// exactly 0.00390625; delta isolates the stagger.

#define NSTEPS 19

typedef _Float16 half8   __attribute__((ext_vector_type(8)));
typedef _Float16 half2v  __attribute__((ext_vector_type(2)));
typedef float    float2v __attribute__((ext_vector_type(2)));
typedef float    float4v __attribute__((ext_vector_type(4)));

__device__ __forceinline__ half2v pkrtz(float a, float b) {
    return __builtin_bit_cast(half2v, __builtin_amdgcn_cvt_pkrtz(a, b));
}
__device__ __forceinline__ float swz_xor16(float v) {
    // BitMode: and=0x1F, or=0, xor=16 -> lane' = lane ^ 16 (within 32-group)
    int r = __builtin_amdgcn_ds_swizzle(__builtin_bit_cast(int, v), 0x401F);
    return __builtin_bit_cast(float, r);
}
__device__ __forceinline__ float2v lo2(float4v v) {
    return __builtin_shufflevector(v, v, 0, 1);
}
__device__ __forceinline__ float2v hi2(float4v v) {
    return __builtin_shufflevector(v, v, 2, 3);
}

__global__ __launch_bounds__(256, 2)
void program_kernel(const float* __restrict__ x,
                    const float* __restrict__ W1,
                    const float* __restrict__ b1,
                    const float* __restrict__ W2,
                    const float* __restrict__ b2,
                    const float* __restrict__ W3,
                    const float* __restrict__ b3,
                    float* __restrict__ out,
                    int B) {
    const int tid    = threadIdx.x;
    const int lane   = tid & 63;
    const int wave   = tid >> 6;
    const int lanelo = lane & 15;   // m: my batch row within the tile
    const int q8     = lane >> 4;   // k-slice / replica group 0..3
    const int myRow  = blockIdx.x * 64 + wave * 16 + lanelo;
    const int rowLd  = myRow < B ? myRow : (B - 1);

    // ---- w1 tables as pairs (VGPR): pair i of kf-half: k = kf*32+q8*8+2i ----
    float2v w1a[8], w1b[8], b1v[8];
    #pragma unroll
    for (int kf = 0; kf < 2; ++kf) {
        const int k0 = kf * 32 + q8 * 8;
        const float2v* a = (const float2v*)(W1 + k0);
        const float2v* bb = (const float2v*)(W1 + 64 + k0);
        const float2v* bv = (const float2v*)(b1 + k0);
        #pragma unroll
        for (int i = 0; i < 4; ++i) {
            w1a[kf * 4 + i] = a[i];
            w1b[kf * 4 + i] = bb[i];
            b1v[kf * 4 + i] = bv[i];
        }
    }

    // ---- W2^T limb A-frags (MFMA-only; AGPR-eligible) ----
    half8 Wh[2][4], Wl[2][4];
    #pragma unroll
    for (int kf = 0; kf < 2; ++kf) {
        #pragma unroll
        for (int t = 0; t < 4; ++t) {
            half8 bh, bl;
            #pragma unroll
            for (int j = 0; j < 8; ++j) {
                const float w =
                    W2[(kf * 32 + q8 * 8 + j) * 64 + t * 16 + lanelo];
                const _Float16 wh = (_Float16)w;                       // RNE
                const _Float16 wl = (_Float16)((w - (float)wh) * 4096.0f);
                bh[j] = wh;
                bl[j] = wl;
            }
            Wh[kf][t] = bh;
            Wl[kf][t] = bl;
        }
    }

    // ---- b2 C-init frags (MFMA-C only) ----
    float4v b2f[4];
    #pragma unroll
    for (int t = 0; t < 4; ++t) {
        const int n = t * 16 + q8 * 4;
        b2f[t] = (float4v){b2[n], b2[n + 1], b2[n + 2], b2[n + 3]};
    }

    // ---- W3 difference tables (VGPR): my n-set n = 16t+4*q8+r, pairs ----
    float2v d10[8], d20[8];
    #pragma unroll
    for (int p = 0; p < 8; ++p) {
        const int n0 = (p >> 1) * 16 + q8 * 4 + (p & 1) * 2;
        const float w00 = W3[n0 * 3 + 0],       w01 = W3[n0 * 3 + 1];
        const float w02 = W3[n0 * 3 + 2];
        const float w10 = W3[(n0 + 1) * 3 + 0], w11 = W3[(n0 + 1) * 3 + 1];
        const float w12 = W3[(n0 + 1) * 3 + 2];
        d10[p] = (float2v){w01 - w00, w11 - w10};
        d20[p] = (float2v){w02 - w00, w12 - w10};
    }
    const float b3v0 = b3[0];
    const float db10 = b3[1] - b3[0];
    const float db20 = b3[2] - b3[0];

    // ---- initial row state (4x replicated across q8 groups) ----
    float pos, fwd, c5;
    {
        const float* xr = x + (size_t)rowLd * 6;
        pos = xr[0];
        fwd = xr[1];
        c5  = xr[5];
    }

    // ---- R13: anti-phase stagger. Co-resident waves on a SIMD occupy
    // different HW wave slots (HW_ID bits [3:0]); odd slots sleep ~640 cyc
    // (half a step) once. No barriers + uniform step durations => the
    // stagger persists, so the two waves' VALU and MFMA phases interleave.
    {
        const unsigned slot =
            __builtin_amdgcn_s_getreg((4 /*HW_ID*/) | (0 << 6) | (3 << 11));
        if (slot & 1) {
            __builtin_amdgcn_s_sleep(10);   // 10*64 = 640 cyc
        }
    }

    const float4v zf = {0.f, 0.f, 0.f, 0.f};
    const float2v z2 = {0.f, 0.f};
    const float2v kinv = {1.0f / 4096.0f, 1.0f / 4096.0f};
    float l0 = 0.f, l1 = 0.f, l2 = 0.f;

    #pragma unroll 1
    for (int step = 0; step < NSTEPS; ++step) {
        // ---- layer 1 (packed) + 2-limb split -> B-frag limbs ----
        const float2v posp = {pos, pos}, fwdp = {fwd, fwd};
        half8 Hh[2], Hl[2];
        #pragma unroll
        for (int kf = 0; kf < 2; ++kf) {
            union { half8 v; half2v h2[4]; } uh, ul;
            #pragma unroll
            for (int p = 0; p < 4; ++p) {
                const int e = kf * 4 + p;
                float2v z = __builtin_elementwise_fma(fwdp, w1b[e], b1v[e]);
                z = __builtin_elementwise_fma(posp, w1a[e], z);
                const float2v hp = __builtin_elementwise_max(z, z2);
                uh.h2[p] = pkrtz(hp[0], hp[1]);
                // residuals (hi-half f16 extract folds into v_fma_mix)
                const float r0 = fmaf((float)uh.h2[p][0], -1.0f, hp[0]);
                const float r1 = fmaf((float)uh.h2[p][1], -1.0f, hp[1]);
                const float2v rp = (float2v){r0, r1} * 4096.0f;  // pk_mul
                ul.h2[p] = pkrtz(rp[0], rp[1]);
            }
            Hh[kf] = uh.v;
            Hl[kf] = ul.v;
        }

        // ---- layer 2 via MFMA (same chain/order as R8) ----
        float4v accA[4], accB[4];
        #pragma unroll
        for (int t = 0; t < 4; ++t) {
            accB[t] = __builtin_amdgcn_mfma_f32_16x16x32_f16(
                Wl[0][t], Hh[0], zf, 0, 0, 0);
            accB[t] = __builtin_amdgcn_mfma_f32_16x16x32_f16(
                Wh[0][t], Hl[0], accB[t], 0, 0, 0);
            accB[t] = __builtin_amdgcn_mfma_f32_16x16x32_f16(
                Wl[1][t], Hh[1], accB[t], 0, 0, 0);
            accB[t] = __builtin_amdgcn_mfma_f32_16x16x32_f16(
                Wh[1][t], Hl[1], accB[t], 0, 0, 0);
            accA[t] = __builtin_amdgcn_mfma_f32_16x16x32_f16(
                Wh[0][t], Hh[0], b2f[t], 0, 0, 0);
            accA[t] = __builtin_amdgcn_mfma_f32_16x16x32_f16(
                Wh[1][t], Hh[1], accA[t], 0, 0, 0);
        }

        // ---- h2 (packed combine+relu) ----
        float2v h2p[8];
        #pragma unroll
        for (int t = 0; t < 4; ++t) {
            h2p[2 * t] = __builtin_elementwise_max(
                __builtin_elementwise_fma(lo2(accB[t]), kinv, lo2(accA[t])),
                z2);
            h2p[2 * t + 1] = __builtin_elementwise_max(
                __builtin_elementwise_fma(hi2(accB[t]), kinv, hi2(accA[t])),
                z2);
        }

        // ---- difference dots (packed) + cross-replica reduce ----
        float2v s1 = z2, s2 = z2;
        #pragma unroll
        for (int p = 0; p < 8; ++p) {
            s1 = __builtin_elementwise_fma(h2p[p], d10[p], s1);
            s2 = __builtin_elementwise_fma(h2p[p], d20[p], s2);
        }
        float g10 = s1[0] + s1[1];
        float g20 = s2[0] + s2[1];
        g10 += swz_xor16(g10);
        g20 += swz_xor16(g20);
        g10 += __shfl_xor(g10, 32, 64);
        g20 += __shfl_xor(g20, 32, 64);
        g10 += db10;   // = l1 - l0
        g20 += db20;   // = l2 - l0

        // ---- last step: reconstruct full logits for the output probs ----
        if (step == NSTEPS - 1) {
            float2v s0 = z2;
            #pragma unroll
            for (int p = 0; p < 8; ++p) {
                const int n0 = (p >> 1) * 16 + q8 * 4 + (p & 1) * 2;
                const float2v w30 = {W3[n0 * 3], W3[(n0 + 1) * 3]};
                s0 = __builtin_elementwise_fma(h2p[p], w30, s0);
            }
            float t0 = s0[0] + s0[1];
            t0 += swz_xor16(t0);
            t0 += __shfl_xor(t0, 32, 64);
            l0 = t0 + b3v0;
            l1 = l0 + g10;
            l2 = l0 + g20;
        }

        // ---- decision: l2 > max(l0,l1) <=> g20 > max(0,g10);
        //      l1 > l0 <=> g10 > 0 (first-max-wins preserved) ----
        const float delta =
            (g20 > fmaxf(0.f, g10)) ? 1.0f : ((g10 > 0.f) ? 0.0f : -1.0f);
        pos += delta;
        fwd += 1.0f;
    }

    // ---- epilogue: all lanes have their row's logits; q8==0 stores ----
    if (q8 == 0 && myRow < B) {
        const float p0 = 1.f / (1.f + __expf(-l0));
        const float p1 = 1.f / (1.f + __expf(-l1));
        const float p2 = 1.f / (1.f + __expf(-l2));
        float2* o = (float2*)(out + (size_t)myRow * 6);
        o[0] = make_float2(pos, fwd);
        o[1] = make_float2(p0, p1);
        o[2] = make_float2(p2, c5 + (float)NSTEPS);
    }
}

extern "C" void kernel_launch(void* const* d_in, const int* in_sizes, int n_in,
                              void* d_out, int out_size, void* d_ws, size_t ws_size,
                              hipStream_t stream) {
    const float* x  = (const float*)d_in[0];
    const float* W1 = (const float*)d_in[1];
    const float* b1 = (const float*)d_in[2];
    const float* W2 = (const float*)d_in[3];
    const float* b2 = (const float*)d_in[4];
    const float* W3 = (const float*)d_in[5];
    const float* b3 = (const float*)d_in[6];
    float* out = (float*)d_out;

    const int B = in_sizes[0] / 6;              // 1048576
    const int nBlocks = (B + 63) / 64;          // 64 rows/block (4 waves x 16)

    program_kernel<<<nBlocks, 256, 0, stream>>>(
        x, W1, b1, W2, b2, W3, b3, out, B);
}